// Round 17
// baseline (126.379 us; speedup 1.0000x reference)
//
#include <hip/hip_runtime.h>

// DigitCapsules dynamic routing. Round-34 = R33 + k_uhat BBAT 8->16.
//  - R33 (DPP stages): 125.7 -> 123.9 us. Remaining pie by the mem-instr
//    issue model: k_uhat 27 us (900 issues/CU), k_iter 2x ~21, pack ~7.
//  - FIX: k_uhat reuses one W load-set for 16 batches (BBAT 16): mem-instrs
//    per u-byte -20% (64 per 2x output vs 40 per 1x). xq staged as two
//    fixed 8-arrays (no internal barrier -> not the R24/R29 residency trap;
//    live set ~128-160 VGPR, under the 2-wave cap). red0 [2][16][16]=2KB;
//    psum write 2 entries/thread. s0 order per (b,c,d) unchanged.
//  - k_pack / k_iter / k_squash byte-identical to R33.
//  - Pipeline (5 launches): k_pack, k_uhat(+s0), k_iter, k_iter, k_squash.
//    Predicted 123.9 -> ~119-121 us; absmax exactly 0.00390625.

#define NCLS   10
#define NCAPS  1152
#define KDO    16
#define CHUNK  128
#define NCH    9           // 1152 / 128
#define NB     256
#define BBAT   16          // batches per k_uhat block (two staged halves)

typedef _Float16 h2_t __attribute__((ext_vector_type(2)));
typedef unsigned u4 __attribute__((ext_vector_type(4)));

static __device__ __forceinline__ unsigned pack2h(float a, float b) {
    union { _Float16 h[2]; unsigned u; } p;
    p.h[0] = (_Float16)a;
    p.h[1] = (_Float16)b;
    return p.u;
}

static __device__ __forceinline__ float dot8h(u4 r, const unsigned* xh) {
    union { unsigned u; h2_t h; } w0, w1, w2, w3, a0, a1, a2, a3;
    w0.u = r.x; w1.u = r.y; w2.u = r.z; w3.u = r.w;
    a0.u = xh[0]; a1.u = xh[1]; a2.u = xh[2]; a3.u = xh[3];
#if __has_builtin(__builtin_amdgcn_fdot2)
    float acc = __builtin_amdgcn_fdot2(w0.h, a0.h, 0.f, false);
    acc = __builtin_amdgcn_fdot2(w1.h, a1.h, acc, false);
    acc = __builtin_amdgcn_fdot2(w2.h, a2.h, acc, false);
    acc = __builtin_amdgcn_fdot2(w3.h, a3.h, acc, false);
    return acc;
#else
    return (float)w0.h.x * (float)a0.h.x + (float)w0.h.y * (float)a0.h.y
         + (float)w1.h.x * (float)a1.h.x + (float)w1.h.y * (float)a1.h.y
         + (float)w2.h.x * (float)a2.h.x + (float)w2.h.y * (float)a2.h.y
         + (float)w3.h.x * (float)a3.h.x + (float)w3.h.y * (float)a3.h.y;
#endif
}

static __device__ __forceinline__ float dot2h(unsigned a, unsigned b, float acc) {
    union { unsigned u; h2_t h; } pa, pb;
    pa.u = a; pb.u = b;
#if __has_builtin(__builtin_amdgcn_fdot2)
    return __builtin_amdgcn_fdot2(pa.h, pb.h, acc, false);
#else
    return acc + (float)pa.h.x * (float)pb.h.x + (float)pa.h.y * (float)pb.h.y;
#endif
}

#if __has_builtin(__builtin_amdgcn_update_dpp)
#define HAVE_DPP 1
// DPP lane exchanges (VALU pipe). All call sites have all 64 lanes active.
static __device__ __forceinline__ float dpp_ror8(float x) {   // lane ^ 8
    int s = (int)__float_as_uint(x);
    return __uint_as_float((unsigned)__builtin_amdgcn_update_dpp(
        s, s, 0x128, 0xF, 0xF, false));                        // row_ror:8
}
static __device__ __forceinline__ float dpp_xor2(float x) {   // lane ^ 2
    int s = (int)__float_as_uint(x);
    return __uint_as_float((unsigned)__builtin_amdgcn_update_dpp(
        s, s, 0x4E, 0xF, 0xF, false));                         // quad {2,3,0,1}
}
static __device__ __forceinline__ float dpp_xor1(float x) {   // lane ^ 1
    int s = (int)__float_as_uint(x);
    return __uint_as_float((unsigned)__builtin_amdgcn_update_dpp(
        s, s, 0xB1, 0xF, 0xF, false));                         // quad {1,0,3,2}
}
#else
#define HAVE_DPP 0
#endif

// Butterfly reduce of 16 per-lane values across a 64-lane wave.
// Lane l ends with S[d(l)], d = (l&4?1:0)|(l&8?2:0)|(l&16?4:0)|(l&32?8:0).
// Stages 32/16: permlane swaps; stages 8/2/1: DPP; stage 4: shfl_xor.
// All variants exchange identical bits in identical add order -> bitwise-
// identical to the pure-shfl version.
static __device__ __forceinline__ float bfly16(const float v[KDO], int lane) {
    float a[8];
#if __has_builtin(__builtin_amdgcn_permlane32_swap)
    #pragma unroll
    for (int i = 0; i < 8; ++i) {
        auto r = __builtin_amdgcn_permlane32_swap(
            __float_as_uint(v[i]), __float_as_uint(v[i + 8]), false, false);
        a[i] = __uint_as_float(r[0]) + __uint_as_float(r[1]);
    }
#else
    #pragma unroll
    for (int i = 0; i < 8; ++i) {
        float send = (lane & 32) ? v[i] : v[i + 8];
        float recv = __shfl_xor(send, 32, 64);
        float keep = (lane & 32) ? v[i + 8] : v[i];
        a[i] = keep + recv;
    }
#endif
    float b[4];
#if __has_builtin(__builtin_amdgcn_permlane16_swap)
    #pragma unroll
    for (int i = 0; i < 4; ++i) {
        auto r = __builtin_amdgcn_permlane16_swap(
            __float_as_uint(a[i]), __float_as_uint(a[i + 4]), false, false);
        b[i] = __uint_as_float(r[0]) + __uint_as_float(r[1]);
    }
#else
    #pragma unroll
    for (int i = 0; i < 4; ++i) {
        float send = (lane & 16) ? a[i] : a[i + 4];
        float recv = __shfl_xor(send, 16, 64);
        float keep = (lane & 16) ? a[i + 4] : a[i];
        b[i] = keep + recv;
    }
#endif
    float c[2];
    #pragma unroll
    for (int i = 0; i < 2; ++i) {
        float send = (lane & 8) ? b[i] : b[i + 2];
#if HAVE_DPP
        float recv = dpp_ror8(send);
#else
        float recv = __shfl_xor(send, 8, 64);
#endif
        float keep = (lane & 8) ? b[i + 2] : b[i];
        c[i] = keep + recv;
    }
    float e;
    {
        float send = (lane & 4) ? c[0] : c[1];
        float recv = __shfl_xor(send, 4, 64);       // no DPP encoding for xor4
        float keep = (lane & 4) ? c[1] : c[0];
        e = keep + recv;
    }
#if HAVE_DPP
    e += dpp_xor2(e);
    e += dpp_xor1(e);
#else
    e += __shfl_xor(e, 2, 64);
    e += __shfl_xor(e, 1, 64);
#endif
    return e;
}

static __device__ __forceinline__ int bfly_d(int lane) {
    return ((lane & 4) ? 1 : 0) | ((lane & 8) ? 2 : 0)
         | ((lane & 16) ? 4 : 0) | ((lane & 32) ? 8 : 0);
}

// ---- fused input packing: blocks [0,720) pack W, [720,1872) pack x ----
__global__ __launch_bounds__(256)
void k_pack(const float4* __restrict__ W4, u4* __restrict__ Wt,
            const float4* __restrict__ x4, u4* __restrict__ xp) {
    int bid = blockIdx.x;
    if (bid < 720) {                      // 720*256 == NCLS*NCAPS*KDO exactly
        int tid = bid * 256 + threadIdx.x;          // (c*NCAPS+i)*KDO + d
        int d = tid & 15;
        int rest = tid >> 4;
        int i = rest % NCAPS;
        int c = rest / NCAPS;
        float4 a = W4[2 * tid];
        float4 b = W4[2 * tid + 1];
        u4 o;
        o.x = pack2h(a.x, a.y);
        o.y = pack2h(a.z, a.w);
        o.z = pack2h(b.x, b.y);
        o.w = pack2h(b.z, b.w);
        Wt[(size_t)(c * KDO + d) * NCAPS + i] = o;
    } else {                              // 1152*256 == NB*NCAPS exactly
        int tid = (bid - 720) * 256 + threadIdx.x;  // b*NCAPS + i
        float4 a = x4[2 * tid];
        float4 b = x4[2 * tid + 1];
        u4 o;
        o.x = pack2h(a.x, a.y);
        o.y = pack2h(a.z, a.w);
        o.z = pack2h(b.x, b.y);
        o.w = pack2h(b.z, b.w);
        xp[tid] = o;
    }
}

// ---- phase 1: ut + uniform-weight partial sums (s0).
// grid (NCH, NB/16, 10): 1 class x 16 batches per block, 128 thr = 2 waves.
// One W load-set feeds 16 batches; xq staged as two 8-arrays (no barrier
// inside the loop -> not the across-barrier residency trap).
__global__ __launch_bounds__(CHUNK, 1)
void k_uhat(const u4* __restrict__ Wt, const u4* __restrict__ xp,
            u4* __restrict__ ut, float* __restrict__ psum)
{
    __shared__ float red0[2][BBAT][KDO];           // [wave][k][d], 2 KB
    const int t    = threadIdx.x;
    const int lane = t & 63;
    const int wave = t >> 6;
    const int ii = blockIdx.x * CHUNK + t;
    const int b0 = blockIdx.y * BBAT;
    const int c  = blockIdx.z;
    const int dm = bfly_d(lane);

    const u4* base = Wt + (size_t)c * KDO * NCAPS + ii;
    u4 r[KDO];                                     // 16 W loads, reused 16x
    #pragma unroll
    for (int d = 0; d < KDO; ++d)
        r[d] = base[(size_t)d * NCAPS];            // regular load: W stays L2

    u4 xqA[8], xqB[8];
    #pragma unroll
    for (int k = 0; k < 8; ++k)
        xqA[k] = xp[(size_t)(b0 + k) * NCAPS + ii];
    #pragma unroll
    for (int k = 0; k < 8; ++k)
        xqB[k] = xp[(size_t)(b0 + 8 + k) * NCAPS + ii];

    #pragma unroll
    for (int k = 0; k < BBAT; ++k) {
        const unsigned* xh = (k < 8) ? (const unsigned*)&xqA[k]
                                     : (const unsigned*)&xqB[k - 8];
        u4 h0, h1;
        float sacc[KDO];                           // f32 u before f16 rounding
        #pragma unroll
        for (int dp = 0; dp < 8; ++dp) {
            float u0 = dot8h(r[2 * dp],     xh);
            float u1 = dot8h(r[2 * dp + 1], xh);
            sacc[2 * dp]     = u0;
            sacc[2 * dp + 1] = u1;
            unsigned pk = pack2h(u0, u1);
            if (dp < 4) ((unsigned*)&h0)[dp] = pk;
            else        ((unsigned*)&h1)[dp - 4] = pk;
        }
        u4* utb = ut + (size_t)(b0 + k) * NCLS * 2 * NCAPS;
        utb[((size_t)c * 2 + 0) * NCAPS + ii] = h0;
        utb[((size_t)c * 2 + 1) * NCAPS + ii] = h1;

        float e = bfly16(sacc, lane);
        if ((lane & 3) == 0) red0[wave][k][dm] = e;
    }
    __syncthreads();
    // 16k x 16d = 256 entries, 128 threads -> 2 per thread strided
    for (int tt = t; tt < BBAT * KDO; tt += CHUNK) {
        int k = tt >> 4, d = tt & 15;
        float v = red0[0][k][d] + red0[1][k][d];
        psum[(((size_t)(b0 + k) * NCH + blockIdx.x) * NCLS + c) * KDO + d] = v;
    }
}

// ---- phase 2 (fused, x2): in-block v from psum + agreement + softmax +
// weighted partial-sum. grid (NCH, NB), 256 threads = 4 waves:
// wave = (class-half<<1) | capsule-subchunk; each thread owns 1 capsule x
// 5 classes (10 u4). Softmax max/den exchanged with partner t^128 via LDS.
__global__ __launch_bounds__(256)
void k_iter(const u4* __restrict__ ut,
            const float* __restrict__ psA, float scaleA,
            const float* __restrict__ psB,
            float* __restrict__ psOut)
{
    __shared__ __align__(16) float s0sh[NCLS * KDO];
    __shared__ __align__(16) float s1sh[NCLS * KDO];
    __shared__ float scsh[2][NCLS];
    __shared__ unsigned vsh[NCLS * 8];
    __shared__ float red[4][5 * KDO];                  // [wave][5c x 16d]
    __shared__ float msh[256];                         // softmax max exchange
    __shared__ float dsh[256];                         // softmax den exchange
    const int t    = threadIdx.x;
    const int lane = t & 63;
    const int wave = t >> 6;                           // 0..3
    const int sub  = wave & 1;                         // capsule subchunk
    const int half = wave >> 1;                        // class half (0/1)
    const int c0   = half * 5;
    const int ii   = blockIdx.x * CHUNK + sub * 64 + lane;
    const int b    = blockIdx.y;
    const int dm   = bfly_d(lane);

    // ---- in-block squash: s = sum of 9 chunk partials (float4) ----
    if (t < 40) {                                      // wave0: psA
        const float4* pA4 = (const float4*)psA + (size_t)b * NCH * 40;
        float4 s = {0.f, 0.f, 0.f, 0.f};
        #pragma unroll
        for (int ch = 0; ch < NCH; ++ch) {
            float4 v = pA4[ch * 40 + t];
            s.x += v.x; s.y += v.y; s.z += v.z; s.w += v.w;
        }
        float4 o = {s.x * scaleA, s.y * scaleA, s.z * scaleA, s.w * scaleA};
        ((float4*)s0sh)[t] = o;
    } else if (psB && t >= 64 && t < 104) {            // wave1: psB
        const int j = t - 64;
        const float4* pB4 = (const float4*)psB + (size_t)b * NCH * 40;
        float4 s = {0.f, 0.f, 0.f, 0.f};
        #pragma unroll
        for (int ch = 0; ch < NCH; ++ch) {
            float4 v = pB4[ch * 40 + j];
            s.x += v.x; s.y += v.y; s.z += v.z; s.w += v.w;
        }
        ((float4*)s1sh)[j] = s;
    }
    __syncthreads();
    if (t < (psB ? 2 * NCLS : NCLS)) {
        int which = t >= NCLS;
        int c = which ? t - NCLS : t;
        const float* ss = which ? s1sh : s0sh;
        float nsq = 0.f;
        #pragma unroll
        for (int d = 0; d < KDO; ++d) {
            float x = ss[c * KDO + d];
            nsq += x * x;
        }
        scsh[which][c] = sqrtf(nsq) / (1.f + nsq);
    }
    __syncthreads();
    if (t < NCLS * 8) {
        int c = t >> 3, dp = t & 7;
        float va = s0sh[c * KDO + 2 * dp]     * scsh[0][c];
        float vb = s0sh[c * KDO + 2 * dp + 1] * scsh[0][c];
        if (psB) {
            va += s1sh[c * KDO + 2 * dp]     * scsh[1][c];
            vb += s1sh[c * KDO + 2 * dp + 1] * scsh[1][c];
        }
        vsh[t] = pack2h(va, vb);
    }
    __syncthreads();

    // ---- load u for this thread's capsule, its 5 classes ----
    const u4* utb = ut + (size_t)b * NCLS * 2 * NCAPS;
    u4 up0[5], up1[5];
    #pragma unroll
    for (int j = 0; j < 5; ++j) {
        int c = c0 + j;
        up0[j] = utb[((size_t)c * 2 + 0) * NCAPS + ii];
        up1[j] = utb[((size_t)c * 2 + 1) * NCAPS + ii];
    }

    // ---- logits for 5 classes ----
    float bl[5];
    #pragma unroll
    for (int j = 0; j < 5; ++j) {
        int c = c0 + j;
        float a = 0.f;
        #pragma unroll
        for (int dp = 0; dp < 4; ++dp)
            a = dot2h(((const unsigned*)&up0[j])[dp], vsh[c * 8 + dp], a);
        #pragma unroll
        for (int dp = 0; dp < 4; ++dp)
            a = dot2h(((const unsigned*)&up1[j])[dp], vsh[c * 8 + 4 + dp], a);
        bl[j] = a;
    }

    // ---- softmax across 10 classes: exchange with partner (t^128) ----
    float m5 = bl[0];
    #pragma unroll
    for (int j = 1; j < 5; ++j) m5 = fmaxf(m5, bl[j]);
    msh[t] = m5;
    __syncthreads();
    float m = fmaxf(m5, msh[t ^ 128]);
    float dp5 = 0.f;
    #pragma unroll
    for (int j = 0; j < 5; ++j) dp5 += __expf(bl[j] - m);
    dsh[t] = dp5;
    __syncthreads();
    float sid = 1.f / (dp5 + dsh[t ^ 128]);
    #pragma unroll
    for (int j = 0; j < 5; ++j) bl[j] = __expf(bl[j] - m) * sid;  // bl := w

    // ---- weighted sum, butterfly reduce per class over this wave ----
    #pragma unroll
    for (int j = 0; j < 5; ++j) {
        float sacc[KDO];
        #pragma unroll
        for (int dp = 0; dp < 8; ++dp) {
            union { unsigned u; h2_t h; } p;
            p.u = (dp < 4) ? ((const unsigned*)&up0[j])[dp]
                           : ((const unsigned*)&up1[j])[dp - 4];
            sacc[2 * dp]     = bl[j] * (float)p.h.x;
            sacc[2 * dp + 1] = bl[j] * (float)p.h.y;
        }
        float e = bfly16(sacc, lane);
        if ((lane & 3) == 0) red[wave][j * KDO + dm] = e;
    }
    __syncthreads();
    if (t < 40) {                                      // float4 psOut write
        // t<20: classes 0-4 in waves 0,1 (idx 4t); t>=20: classes 5-9 in
        // waves 2,3 (idx 4(t-20)).
        int w0 = (t < 20) ? 0 : 2;
        int ix = (t < 20) ? 4 * t : 4 * (t - 20);
        float4 o;
        o.x = red[w0][ix + 0] + red[w0 + 1][ix + 0];
        o.y = red[w0][ix + 1] + red[w0 + 1][ix + 1];
        o.z = red[w0][ix + 2] + red[w0 + 1][ix + 2];
        o.w = red[w0][ix + 3] + red[w0 + 1][ix + 3];
        ((float4*)(psOut + ((size_t)b * NCH + blockIdx.x) * (NCLS * KDO)))[t] = o;
    }
}

// ---- phase 3 (final only): sum 9 chunk-partials (float4), squash, out.
__global__ __launch_bounds__(160)
void k_squash(const float* __restrict__ psum, float* __restrict__ out)
{
    __shared__ __align__(16) float ssh[NCLS * KDO];
    const int b = blockIdx.x;
    const int t = threadIdx.x;                         // 0..159

    if (t < 40) {
        const float4* p4 = (const float4*)psum + (size_t)b * NCH * 40;
        float4 s = {0.f, 0.f, 0.f, 0.f};
        #pragma unroll
        for (int ch = 0; ch < NCH; ++ch) {
            float4 v = p4[ch * 40 + t];
            s.x += v.x; s.y += v.y; s.z += v.z; s.w += v.w;
        }
        ((float4*)ssh)[t] = s;
    }
    __syncthreads();
    if (t >= NCLS * KDO) return;

    float s = ssh[t];
    float nsq = s * s;                                 // reduce within c-group
    nsq += __shfl_xor(nsq, 8, 16);
    nsq += __shfl_xor(nsq, 4, 16);
    nsq += __shfl_xor(nsq, 2, 16);
    nsq += __shfl_xor(nsq, 1, 16);
    float sc = sqrtf(nsq) / (1.f + nsq);               // (nsq/(1+nsq))/sqrt(nsq)
    out[(size_t)b * NCLS * KDO + t] = s * sc;
}

// ---- fallback (small ws): round-1 fp32 fused kernel, proven correct ----
__global__ __launch_bounds__(256, 2)
void caps_routing_fb(const float* __restrict__ x, const float* __restrict__ W,
                     float* __restrict__ out)
{
    const int b    = blockIdx.x;
    const int t    = threadIdx.x;
    const int lane = t & 63;
    const int wave = t >> 6;
    __shared__ float v_prev[NCLS * KDO];
    __shared__ float redf[NCLS * 4 * KDO];
    float4 xr[5][2];
    const float4* x4 = reinterpret_cast<const float4*>(x + (size_t)b * NCAPS * 8);
    #pragma unroll
    for (int j = 0; j < 5; ++j) {
        int i = t + 256 * j;
        if (i < NCAPS) { xr[j][0] = x4[2 * i]; xr[j][1] = x4[2 * i + 1]; }
    }
    float blog[5][NCLS];
    #pragma unroll
    for (int j = 0; j < 5; ++j)
        #pragma unroll
        for (int c = 0; c < NCLS; ++c) blog[j][c] = 0.f;
    const float4* W4 = reinterpret_cast<const float4*>(W);
    for (int it = 0; it < 3; ++it) {
        if (it > 0) {
            for (int c = 0; c < NCLS; ++c) {
                float vp[KDO];
                #pragma unroll
                for (int d = 0; d < KDO; ++d) vp[d] = v_prev[c * KDO + d];
                #pragma unroll
                for (int j = 0; j < 5; ++j) {
                    int i = t + 256 * j;
                    if (i < NCAPS) {
                        size_t wbx = (size_t)(c * NCAPS + i) * 32;
                        float a = 0.f;
                        #pragma unroll
                        for (int d = 0; d < KDO; ++d) {
                            float4 w0 = W4[wbx + 2 * d]; float4 w1 = W4[wbx + 2 * d + 1];
                            float u = w0.x*xr[j][0].x + w0.y*xr[j][0].y + w0.z*xr[j][0].z
                                    + w0.w*xr[j][0].w + w1.x*xr[j][1].x + w1.y*xr[j][1].y
                                    + w1.z*xr[j][1].z + w1.w*xr[j][1].w;
                            a += u * vp[d];
                        }
                        blog[j][c] += a;
                    }
                }
            }
        }
        float sm2[5], sid2[5];
        #pragma unroll
        for (int j = 0; j < 5; ++j) {
            int i = t + 256 * j;
            if (i < NCAPS) {
                float m = blog[j][0];
                #pragma unroll
                for (int c = 1; c < NCLS; ++c) m = fmaxf(m, blog[j][c]);
                float den = 0.f;
                #pragma unroll
                for (int c = 0; c < NCLS; ++c) den += __expf(blog[j][c] - m);
                sm2[j] = m; sid2[j] = 1.f / den;
            }
        }
        for (int c = 0; c < NCLS; ++c) {
            float acc[KDO];
            #pragma unroll
            for (int d = 0; d < KDO; ++d) acc[d] = 0.f;
            #pragma unroll
            for (int j = 0; j < 5; ++j) {
                int i = t + 256 * j;
                if (i < NCAPS) {
                    float wq = __expf(blog[j][c] - sm2[j]) * sid2[j];
                    size_t wbx = (size_t)(c * NCAPS + i) * 32;
                    #pragma unroll
                    for (int d = 0; d < KDO; ++d) {
                        float4 w0 = W4[wbx + 2 * d]; float4 w1 = W4[wbx + 2 * d + 1];
                        float u = w0.x*xr[j][0].x + w0.y*xr[j][0].y + w0.z*xr[j][0].z
                                + w0.w*xr[j][0].w + w1.x*xr[j][1].x + w1.y*xr[j][1].y
                                + w1.z*xr[j][1].z + w1.w*xr[j][1].w;
                        acc[d] += wq * u;
                    }
                }
            }
            #pragma unroll
            for (int d = 0; d < KDO; ++d) {
                float v = acc[d];
                v += __shfl_xor(v, 32, 64); v += __shfl_xor(v, 16, 64);
                v += __shfl_xor(v,  8, 64); v += __shfl_xor(v,  4, 64);
                v += __shfl_xor(v,  2, 64); v += __shfl_xor(v,  1, 64);
                if (lane == 0) redf[(c * 4 + wave) * KDO + d] = v;
            }
        }
        __syncthreads();
        if (t < NCLS * KDO) {
            int c = t >> 4, d = t & 15;
            float s = redf[(c*4+0)*KDO+d] + redf[(c*4+1)*KDO+d]
                    + redf[(c*4+2)*KDO+d] + redf[(c*4+3)*KDO+d];
            float nsq = s * s;
            nsq += __shfl_xor(nsq, 8, 16); nsq += __shfl_xor(nsq, 4, 16);
            nsq += __shfl_xor(nsq, 2, 16); nsq += __shfl_xor(nsq, 1, 16);
            float scale = sqrtf(nsq) / (1.f + nsq);
            float vv = s * scale;
            v_prev[t] = vv;
            if (it == 2) out[(size_t)b * NCLS * KDO + t] = vv;
        }
        __syncthreads();
    }
}

extern "C" void kernel_launch(void* const* d_in, const int* in_sizes, int n_in,
                              void* d_out, int out_size, void* d_ws, size_t ws_size,
                              hipStream_t stream) {
    const float* x = (const float*)d_in[0];              // [256, 1152, 8] fp32
    const float4* W4 = (const float4*)d_in[1];           // [10, 1152, 1, 16, 8] fp32
    float* out = (float*)d_out;                          // [256, 10, 1, 16] fp32
    (void)in_sizes; (void)n_in; (void)out_size;

    const size_t WT = (size_t)NCLS * KDO * NCAPS * sizeof(u4);            //  2.95 MB
    const size_t XH = (size_t)NB * NCAPS * sizeof(u4);                    //  4.72 MB
    const size_t UT = (size_t)NB * NCLS * 2 * NCAPS * sizeof(u4);         // 94.37 MB
    const size_t PS = (size_t)NB * NCH * NCLS * KDO * sizeof(float);      //  1.47 MB
    const size_t need = WT + XH + UT + 3 * PS;                            // ~106 MB

    if (ws_size >= need) {
        char* p = (char*)d_ws;
        u4* Wt    = (u4*)p;    p += WT;
        u4* xp    = (u4*)p;    p += XH;
        u4* ut    = (u4*)p;    p += UT;
        float* ps0 = (float*)p; p += PS;
        float* ps1 = (float*)p; p += PS;
        float* ps2 = (float*)p;

        k_pack<<<dim3(720 + 1152), dim3(256), 0, stream>>>(
            W4, Wt, (const float4*)x, xp);
        k_uhat<<<dim3(NCH, NB / BBAT, NCLS), dim3(CHUNK), 0, stream>>>(
            Wt, xp, ut, ps0);
        k_iter<<<dim3(NCH, NB), dim3(256), 0, stream>>>(ut, ps0, 0.1f, nullptr, ps1);
        k_iter<<<dim3(NCH, NB), dim3(256), 0, stream>>>(ut, ps0, 0.1f, ps1, ps2);
        k_squash<<<dim3(NB), dim3(160), 0, stream>>>(ps2, out);
    } else {
        caps_routing_fb<<<dim3(NB), dim3(256), 0, stream>>>(x, (const float*)d_in[1], out);
    }
}

// Round 18
// 122.614 us; speedup vs baseline: 1.0307x; 1.0307x over previous
//
#include <hip/hip_runtime.h>

// DigitCapsules dynamic routing. Round-35 = EXACT revert to R33 (123.9 us).
//  - R34 LESSON: BBAT 8->16 halved the k_uhat grid (5.6 -> 2.8 waves/SIMD);
//    latency-hiding loss (+VGPR pressure) beat the -20% mem-instr saving
//    (126.4 us). These kernels are latency-bound: wave count > instr count
//    once instrs/byte is lean. Reverted to BBAT=8.
//  - Session ledger: fusion -84, butterfly -30, BBAT4->8/L2 W -25, permlane
//    +DPP -7, class-split -4. Failed: mega-kernel (spill), cooperative
//    (capture crash), atomic tail (regalloc poison), load hoist (spill),
//    BBAT16 (occupancy). 5-launch latency-bound floor ~124 us.
//  - Pipeline: k_pack, k_uhat(+s0), k_iter, k_iter, k_squash.

#define NCLS   10
#define NCAPS  1152
#define KDO    16
#define CHUNK  128
#define NCH    9           // 1152 / 128
#define NB     256
#define BBAT   8           // batches per k_uhat block

typedef _Float16 h2_t __attribute__((ext_vector_type(2)));
typedef unsigned u4 __attribute__((ext_vector_type(4)));

static __device__ __forceinline__ unsigned pack2h(float a, float b) {
    union { _Float16 h[2]; unsigned u; } p;
    p.h[0] = (_Float16)a;
    p.h[1] = (_Float16)b;
    return p.u;
}

static __device__ __forceinline__ float dot8h(u4 r, const unsigned* xh) {
    union { unsigned u; h2_t h; } w0, w1, w2, w3, a0, a1, a2, a3;
    w0.u = r.x; w1.u = r.y; w2.u = r.z; w3.u = r.w;
    a0.u = xh[0]; a1.u = xh[1]; a2.u = xh[2]; a3.u = xh[3];
#if __has_builtin(__builtin_amdgcn_fdot2)
    float acc = __builtin_amdgcn_fdot2(w0.h, a0.h, 0.f, false);
    acc = __builtin_amdgcn_fdot2(w1.h, a1.h, acc, false);
    acc = __builtin_amdgcn_fdot2(w2.h, a2.h, acc, false);
    acc = __builtin_amdgcn_fdot2(w3.h, a3.h, acc, false);
    return acc;
#else
    return (float)w0.h.x * (float)a0.h.x + (float)w0.h.y * (float)a0.h.y
         + (float)w1.h.x * (float)a1.h.x + (float)w1.h.y * (float)a1.h.y
         + (float)w2.h.x * (float)a2.h.x + (float)w2.h.y * (float)a2.h.y
         + (float)w3.h.x * (float)a3.h.x + (float)w3.h.y * (float)a3.h.y;
#endif
}

static __device__ __forceinline__ float dot2h(unsigned a, unsigned b, float acc) {
    union { unsigned u; h2_t h; } pa, pb;
    pa.u = a; pb.u = b;
#if __has_builtin(__builtin_amdgcn_fdot2)
    return __builtin_amdgcn_fdot2(pa.h, pb.h, acc, false);
#else
    return acc + (float)pa.h.x * (float)pb.h.x + (float)pa.h.y * (float)pb.h.y;
#endif
}

#if __has_builtin(__builtin_amdgcn_update_dpp)
#define HAVE_DPP 1
// DPP lane exchanges (VALU pipe). All call sites have all 64 lanes active.
static __device__ __forceinline__ float dpp_ror8(float x) {   // lane ^ 8
    int s = (int)__float_as_uint(x);
    return __uint_as_float((unsigned)__builtin_amdgcn_update_dpp(
        s, s, 0x128, 0xF, 0xF, false));                        // row_ror:8
}
static __device__ __forceinline__ float dpp_xor2(float x) {   // lane ^ 2
    int s = (int)__float_as_uint(x);
    return __uint_as_float((unsigned)__builtin_amdgcn_update_dpp(
        s, s, 0x4E, 0xF, 0xF, false));                         // quad {2,3,0,1}
}
static __device__ __forceinline__ float dpp_xor1(float x) {   // lane ^ 1
    int s = (int)__float_as_uint(x);
    return __uint_as_float((unsigned)__builtin_amdgcn_update_dpp(
        s, s, 0xB1, 0xF, 0xF, false));                         // quad {1,0,3,2}
}
#else
#define HAVE_DPP 0
#endif

// Butterfly reduce of 16 per-lane values across a 64-lane wave.
// Lane l ends with S[d(l)], d = (l&4?1:0)|(l&8?2:0)|(l&16?4:0)|(l&32?8:0).
// Stages 32/16: permlane swaps; stages 8/2/1: DPP; stage 4: shfl_xor.
// All variants exchange identical bits in identical add order -> bitwise-
// identical to the pure-shfl version.
static __device__ __forceinline__ float bfly16(const float v[KDO], int lane) {
    float a[8];
#if __has_builtin(__builtin_amdgcn_permlane32_swap)
    #pragma unroll
    for (int i = 0; i < 8; ++i) {
        auto r = __builtin_amdgcn_permlane32_swap(
            __float_as_uint(v[i]), __float_as_uint(v[i + 8]), false, false);
        a[i] = __uint_as_float(r[0]) + __uint_as_float(r[1]);
    }
#else
    #pragma unroll
    for (int i = 0; i < 8; ++i) {
        float send = (lane & 32) ? v[i] : v[i + 8];
        float recv = __shfl_xor(send, 32, 64);
        float keep = (lane & 32) ? v[i + 8] : v[i];
        a[i] = keep + recv;
    }
#endif
    float b[4];
#if __has_builtin(__builtin_amdgcn_permlane16_swap)
    #pragma unroll
    for (int i = 0; i < 4; ++i) {
        auto r = __builtin_amdgcn_permlane16_swap(
            __float_as_uint(a[i]), __float_as_uint(a[i + 4]), false, false);
        b[i] = __uint_as_float(r[0]) + __uint_as_float(r[1]);
    }
#else
    #pragma unroll
    for (int i = 0; i < 4; ++i) {
        float send = (lane & 16) ? a[i] : a[i + 4];
        float recv = __shfl_xor(send, 16, 64);
        float keep = (lane & 16) ? a[i + 4] : a[i];
        b[i] = keep + recv;
    }
#endif
    float c[2];
    #pragma unroll
    for (int i = 0; i < 2; ++i) {
        float send = (lane & 8) ? b[i] : b[i + 2];
#if HAVE_DPP
        float recv = dpp_ror8(send);
#else
        float recv = __shfl_xor(send, 8, 64);
#endif
        float keep = (lane & 8) ? b[i + 2] : b[i];
        c[i] = keep + recv;
    }
    float e;
    {
        float send = (lane & 4) ? c[0] : c[1];
        float recv = __shfl_xor(send, 4, 64);       // no DPP encoding for xor4
        float keep = (lane & 4) ? c[1] : c[0];
        e = keep + recv;
    }
#if HAVE_DPP
    e += dpp_xor2(e);
    e += dpp_xor1(e);
#else
    e += __shfl_xor(e, 2, 64);
    e += __shfl_xor(e, 1, 64);
#endif
    return e;
}

static __device__ __forceinline__ int bfly_d(int lane) {
    return ((lane & 4) ? 1 : 0) | ((lane & 8) ? 2 : 0)
         | ((lane & 16) ? 4 : 0) | ((lane & 32) ? 8 : 0);
}

// ---- fused input packing: blocks [0,720) pack W, [720,1872) pack x ----
__global__ __launch_bounds__(256)
void k_pack(const float4* __restrict__ W4, u4* __restrict__ Wt,
            const float4* __restrict__ x4, u4* __restrict__ xp) {
    int bid = blockIdx.x;
    if (bid < 720) {                      // 720*256 == NCLS*NCAPS*KDO exactly
        int tid = bid * 256 + threadIdx.x;          // (c*NCAPS+i)*KDO + d
        int d = tid & 15;
        int rest = tid >> 4;
        int i = rest % NCAPS;
        int c = rest / NCAPS;
        float4 a = W4[2 * tid];
        float4 b = W4[2 * tid + 1];
        u4 o;
        o.x = pack2h(a.x, a.y);
        o.y = pack2h(a.z, a.w);
        o.z = pack2h(b.x, b.y);
        o.w = pack2h(b.z, b.w);
        Wt[(size_t)(c * KDO + d) * NCAPS + i] = o;
    } else {                              // 1152*256 == NB*NCAPS exactly
        int tid = (bid - 720) * 256 + threadIdx.x;  // b*NCAPS + i
        float4 a = x4[2 * tid];
        float4 b = x4[2 * tid + 1];
        u4 o;
        o.x = pack2h(a.x, a.y);
        o.y = pack2h(a.z, a.w);
        o.z = pack2h(b.x, b.y);
        o.w = pack2h(b.z, b.w);
        xp[tid] = o;
    }
}

// ---- phase 1: ut + uniform-weight partial sums (s0).
// grid (NCH, NB/8, 10): 1 class x 8 batches per block, 128 threads = 2 waves.
__global__ __launch_bounds__(CHUNK, 1)
void k_uhat(const u4* __restrict__ Wt, const u4* __restrict__ xp,
            u4* __restrict__ ut, float* __restrict__ psum)
{
    __shared__ float red0[2][BBAT][KDO];           // [wave][k][d], 1 KB
    const int t    = threadIdx.x;
    const int lane = t & 63;
    const int wave = t >> 6;
    const int ii = blockIdx.x * CHUNK + t;
    const int b0 = blockIdx.y * BBAT;
    const int c  = blockIdx.z;
    const int dm = bfly_d(lane);

    u4 xq[BBAT];
    #pragma unroll
    for (int k = 0; k < BBAT; ++k)
        xq[k] = xp[(size_t)(b0 + k) * NCAPS + ii];

    const u4* base = Wt + (size_t)c * KDO * NCAPS + ii;
    u4 r[KDO];                                     // 16 loads in flight
    #pragma unroll
    for (int d = 0; d < KDO; ++d)
        r[d] = base[(size_t)d * NCAPS];            // regular load: W stays L2

    #pragma unroll
    for (int k = 0; k < BBAT; ++k) {               // reuse W for 8 batches
        const unsigned* xh = (const unsigned*)&xq[k];
        u4 h0, h1;
        float sacc[KDO];                           // f32 u before f16 rounding
        #pragma unroll
        for (int dp = 0; dp < 8; ++dp) {
            float u0 = dot8h(r[2 * dp],     xh);
            float u1 = dot8h(r[2 * dp + 1], xh);
            sacc[2 * dp]     = u0;
            sacc[2 * dp + 1] = u1;
            unsigned pk = pack2h(u0, u1);
            if (dp < 4) ((unsigned*)&h0)[dp] = pk;
            else        ((unsigned*)&h1)[dp - 4] = pk;
        }
        u4* utb = ut + (size_t)(b0 + k) * NCLS * 2 * NCAPS;
        utb[((size_t)c * 2 + 0) * NCAPS + ii] = h0;
        utb[((size_t)c * 2 + 1) * NCAPS + ii] = h1;

        float e = bfly16(sacc, lane);
        if ((lane & 3) == 0) red0[wave][k][dm] = e;
    }
    __syncthreads();
    {   // 8k x 16d = 128 entries, exactly one per thread
        int k = t >> 4, d = t & 15;
        float v = red0[0][k][d] + red0[1][k][d];
        psum[(((size_t)(b0 + k) * NCH + blockIdx.x) * NCLS + c) * KDO + d] = v;
    }
}

// ---- phase 2 (fused, x2): in-block v from psum + agreement + softmax +
// weighted partial-sum. grid (NCH, NB), 256 threads = 4 waves:
// wave = (class-half<<1) | capsule-subchunk; each thread owns 1 capsule x
// 5 classes (10 u4). Softmax max/den exchanged with partner t^128 via LDS.
__global__ __launch_bounds__(256)
void k_iter(const u4* __restrict__ ut,
            const float* __restrict__ psA, float scaleA,
            const float* __restrict__ psB,
            float* __restrict__ psOut)
{
    __shared__ __align__(16) float s0sh[NCLS * KDO];
    __shared__ __align__(16) float s1sh[NCLS * KDO];
    __shared__ float scsh[2][NCLS];
    __shared__ unsigned vsh[NCLS * 8];
    __shared__ float red[4][5 * KDO];                  // [wave][5c x 16d]
    __shared__ float msh[256];                         // softmax max exchange
    __shared__ float dsh[256];                         // softmax den exchange
    const int t    = threadIdx.x;
    const int lane = t & 63;
    const int wave = t >> 6;                           // 0..3
    const int sub  = wave & 1;                         // capsule subchunk
    const int half = wave >> 1;                        // class half (0/1)
    const int c0   = half * 5;
    const int ii   = blockIdx.x * CHUNK + sub * 64 + lane;
    const int b    = blockIdx.y;
    const int dm   = bfly_d(lane);

    // ---- in-block squash: s = sum of 9 chunk partials (float4) ----
    if (t < 40) {                                      // wave0: psA
        const float4* pA4 = (const float4*)psA + (size_t)b * NCH * 40;
        float4 s = {0.f, 0.f, 0.f, 0.f};
        #pragma unroll
        for (int ch = 0; ch < NCH; ++ch) {
            float4 v = pA4[ch * 40 + t];
            s.x += v.x; s.y += v.y; s.z += v.z; s.w += v.w;
        }
        float4 o = {s.x * scaleA, s.y * scaleA, s.z * scaleA, s.w * scaleA};
        ((float4*)s0sh)[t] = o;
    } else if (psB && t >= 64 && t < 104) {            // wave1: psB
        const int j = t - 64;
        const float4* pB4 = (const float4*)psB + (size_t)b * NCH * 40;
        float4 s = {0.f, 0.f, 0.f, 0.f};
        #pragma unroll
        for (int ch = 0; ch < NCH; ++ch) {
            float4 v = pB4[ch * 40 + j];
            s.x += v.x; s.y += v.y; s.z += v.z; s.w += v.w;
        }
        ((float4*)s1sh)[j] = s;
    }
    __syncthreads();
    if (t < (psB ? 2 * NCLS : NCLS)) {
        int which = t >= NCLS;
        int c = which ? t - NCLS : t;
        const float* ss = which ? s1sh : s0sh;
        float nsq = 0.f;
        #pragma unroll
        for (int d = 0; d < KDO; ++d) {
            float x = ss[c * KDO + d];
            nsq += x * x;
        }
        scsh[which][c] = sqrtf(nsq) / (1.f + nsq);
    }
    __syncthreads();
    if (t < NCLS * 8) {
        int c = t >> 3, dp = t & 7;
        float va = s0sh[c * KDO + 2 * dp]     * scsh[0][c];
        float vb = s0sh[c * KDO + 2 * dp + 1] * scsh[0][c];
        if (psB) {
            va += s1sh[c * KDO + 2 * dp]     * scsh[1][c];
            vb += s1sh[c * KDO + 2 * dp + 1] * scsh[1][c];
        }
        vsh[t] = pack2h(va, vb);
    }
    __syncthreads();

    // ---- load u for this thread's capsule, its 5 classes ----
    const u4* utb = ut + (size_t)b * NCLS * 2 * NCAPS;
    u4 up0[5], up1[5];
    #pragma unroll
    for (int j = 0; j < 5; ++j) {
        int c = c0 + j;
        up0[j] = utb[((size_t)c * 2 + 0) * NCAPS + ii];
        up1[j] = utb[((size_t)c * 2 + 1) * NCAPS + ii];
    }

    // ---- logits for 5 classes ----
    float bl[5];
    #pragma unroll
    for (int j = 0; j < 5; ++j) {
        int c = c0 + j;
        float a = 0.f;
        #pragma unroll
        for (int dp = 0; dp < 4; ++dp)
            a = dot2h(((const unsigned*)&up0[j])[dp], vsh[c * 8 + dp], a);
        #pragma unroll
        for (int dp = 0; dp < 4; ++dp)
            a = dot2h(((const unsigned*)&up1[j])[dp], vsh[c * 8 + 4 + dp], a);
        bl[j] = a;
    }

    // ---- softmax across 10 classes: exchange with partner (t^128) ----
    float m5 = bl[0];
    #pragma unroll
    for (int j = 1; j < 5; ++j) m5 = fmaxf(m5, bl[j]);
    msh[t] = m5;
    __syncthreads();
    float m = fmaxf(m5, msh[t ^ 128]);
    float dp5 = 0.f;
    #pragma unroll
    for (int j = 0; j < 5; ++j) dp5 += __expf(bl[j] - m);
    dsh[t] = dp5;
    __syncthreads();
    float sid = 1.f / (dp5 + dsh[t ^ 128]);
    #pragma unroll
    for (int j = 0; j < 5; ++j) bl[j] = __expf(bl[j] - m) * sid;  // bl := w

    // ---- weighted sum, butterfly reduce per class over this wave ----
    #pragma unroll
    for (int j = 0; j < 5; ++j) {
        float sacc[KDO];
        #pragma unroll
        for (int dp = 0; dp < 8; ++dp) {
            union { unsigned u; h2_t h; } p;
            p.u = (dp < 4) ? ((const unsigned*)&up0[j])[dp]
                           : ((const unsigned*)&up1[j])[dp - 4];
            sacc[2 * dp]     = bl[j] * (float)p.h.x;
            sacc[2 * dp + 1] = bl[j] * (float)p.h.y;
        }
        float e = bfly16(sacc, lane);
        if ((lane & 3) == 0) red[wave][j * KDO + dm] = e;
    }
    __syncthreads();
    if (t < 40) {                                      // float4 psOut write
        // t<20: classes 0-4 in waves 0,1 (idx 4t); t>=20: classes 5-9 in
        // waves 2,3 (idx 4(t-20)).
        int w0 = (t < 20) ? 0 : 2;
        int ix = (t < 20) ? 4 * t : 4 * (t - 20);
        float4 o;
        o.x = red[w0][ix + 0] + red[w0 + 1][ix + 0];
        o.y = red[w0][ix + 1] + red[w0 + 1][ix + 1];
        o.z = red[w0][ix + 2] + red[w0 + 1][ix + 2];
        o.w = red[w0][ix + 3] + red[w0 + 1][ix + 3];
        ((float4*)(psOut + ((size_t)b * NCH + blockIdx.x) * (NCLS * KDO)))[t] = o;
    }
}

// ---- phase 3 (final only): sum 9 chunk-partials (float4), squash, out.
__global__ __launch_bounds__(160)
void k_squash(const float* __restrict__ psum, float* __restrict__ out)
{
    __shared__ __align__(16) float ssh[NCLS * KDO];
    const int b = blockIdx.x;
    const int t = threadIdx.x;                         // 0..159

    if (t < 40) {
        const float4* p4 = (const float4*)psum + (size_t)b * NCH * 40;
        float4 s = {0.f, 0.f, 0.f, 0.f};
        #pragma unroll
        for (int ch = 0; ch < NCH; ++ch) {
            float4 v = p4[ch * 40 + t];
            s.x += v.x; s.y += v.y; s.z += v.z; s.w += v.w;
        }
        ((float4*)ssh)[t] = s;
    }
    __syncthreads();
    if (t >= NCLS * KDO) return;

    float s = ssh[t];
    float nsq = s * s;                                 // reduce within c-group
    nsq += __shfl_xor(nsq, 8, 16);
    nsq += __shfl_xor(nsq, 4, 16);
    nsq += __shfl_xor(nsq, 2, 16);
    nsq += __shfl_xor(nsq, 1, 16);
    float sc = sqrtf(nsq) / (1.f + nsq);               // (nsq/(1+nsq))/sqrt(nsq)
    out[(size_t)b * NCLS * KDO + t] = s * sc;
}

// ---- fallback (small ws): round-1 fp32 fused kernel, proven correct ----
__global__ __launch_bounds__(256, 2)
void caps_routing_fb(const float* __restrict__ x, const float* __restrict__ W,
                     float* __restrict__ out)
{
    const int b    = blockIdx.x;
    const int t    = threadIdx.x;
    const int lane = t & 63;
    const int wave = t >> 6;
    __shared__ float v_prev[NCLS * KDO];
    __shared__ float redf[NCLS * 4 * KDO];
    float4 xr[5][2];
    const float4* x4 = reinterpret_cast<const float4*>(x + (size_t)b * NCAPS * 8);
    #pragma unroll
    for (int j = 0; j < 5; ++j) {
        int i = t + 256 * j;
        if (i < NCAPS) { xr[j][0] = x4[2 * i]; xr[j][1] = x4[2 * i + 1]; }
    }
    float blog[5][NCLS];
    #pragma unroll
    for (int j = 0; j < 5; ++j)
        #pragma unroll
        for (int c = 0; c < NCLS; ++c) blog[j][c] = 0.f;
    const float4* W4 = reinterpret_cast<const float4*>(W);
    for (int it = 0; it < 3; ++it) {
        if (it > 0) {
            for (int c = 0; c < NCLS; ++c) {
                float vp[KDO];
                #pragma unroll
                for (int d = 0; d < KDO; ++d) vp[d] = v_prev[c * KDO + d];
                #pragma unroll
                for (int j = 0; j < 5; ++j) {
                    int i = t + 256 * j;
                    if (i < NCAPS) {
                        size_t wbx = (size_t)(c * NCAPS + i) * 32;
                        float a = 0.f;
                        #pragma unroll
                        for (int d = 0; d < KDO; ++d) {
                            float4 w0 = W4[wbx + 2 * d]; float4 w1 = W4[wbx + 2 * d + 1];
                            float u = w0.x*xr[j][0].x + w0.y*xr[j][0].y + w0.z*xr[j][0].z
                                    + w0.w*xr[j][0].w + w1.x*xr[j][1].x + w1.y*xr[j][1].y
                                    + w1.z*xr[j][1].z + w1.w*xr[j][1].w;
                            a += u * vp[d];
                        }
                        blog[j][c] += a;
                    }
                }
            }
        }
        float sm2[5], sid2[5];
        #pragma unroll
        for (int j = 0; j < 5; ++j) {
            int i = t + 256 * j;
            if (i < NCAPS) {
                float m = blog[j][0];
                #pragma unroll
                for (int c = 1; c < NCLS; ++c) m = fmaxf(m, blog[j][c]);
                float den = 0.f;
                #pragma unroll
                for (int c = 0; c < NCLS; ++c) den += __expf(blog[j][c] - m);
                sm2[j] = m; sid2[j] = 1.f / den;
            }
        }
        for (int c = 0; c < NCLS; ++c) {
            float acc[KDO];
            #pragma unroll
            for (int d = 0; d < KDO; ++d) acc[d] = 0.f;
            #pragma unroll
            for (int j = 0; j < 5; ++j) {
                int i = t + 256 * j;
                if (i < NCAPS) {
                    float wq = __expf(blog[j][c] - sm2[j]) * sid2[j];
                    size_t wbx = (size_t)(c * NCAPS + i) * 32;
                    #pragma unroll
                    for (int d = 0; d < KDO; ++d) {
                        float4 w0 = W4[wbx + 2 * d]; float4 w1 = W4[wbx + 2 * d + 1];
                        float u = w0.x*xr[j][0].x + w0.y*xr[j][0].y + w0.z*xr[j][0].z
                                + w0.w*xr[j][0].w + w1.x*xr[j][1].x + w1.y*xr[j][1].y
                                + w1.z*xr[j][1].z + w1.w*xr[j][1].w;
                        acc[d] += wq * u;
                    }
                }
            }
            #pragma unroll
            for (int d = 0; d < KDO; ++d) {
                float v = acc[d];
                v += __shfl_xor(v, 32, 64); v += __shfl_xor(v, 16, 64);
                v += __shfl_xor(v,  8, 64); v += __shfl_xor(v,  4, 64);
                v += __shfl_xor(v,  2, 64); v += __shfl_xor(v,  1, 64);
                if (lane == 0) redf[(c * 4 + wave) * KDO + d] = v;
            }
        }
        __syncthreads();
        if (t < NCLS * KDO) {
            int c = t >> 4, d = t & 15;
            float s = redf[(c*4+0)*KDO+d] + redf[(c*4+1)*KDO+d]
                    + redf[(c*4+2)*KDO+d] + redf[(c*4+3)*KDO+d];
            float nsq = s * s;
            nsq += __shfl_xor(nsq, 8, 16); nsq += __shfl_xor(nsq, 4, 16);
            nsq += __shfl_xor(nsq, 2, 16); nsq += __shfl_xor(nsq, 1, 16);
            float scale = sqrtf(nsq) / (1.f + nsq);
            float vv = s * scale;
            v_prev[t] = vv;
            if (it == 2) out[(size_t)b * NCLS * KDO + t] = vv;
        }
        __syncthreads();
    }
}

extern "C" void kernel_launch(void* const* d_in, const int* in_sizes, int n_in,
                              void* d_out, int out_size, void* d_ws, size_t ws_size,
                              hipStream_t stream) {
    const float* x = (const float*)d_in[0];              // [256, 1152, 8] fp32
    const float4* W4 = (const float4*)d_in[1];           // [10, 1152, 1, 16, 8] fp32
    float* out = (float*)d_out;                          // [256, 10, 1, 16] fp32
    (void)in_sizes; (void)n_in; (void)out_size;

    const size_t WT = (size_t)NCLS * KDO * NCAPS * sizeof(u4);            //  2.95 MB
    const size_t XH = (size_t)NB * NCAPS * sizeof(u4);                    //  4.72 MB
    const size_t UT = (size_t)NB * NCLS * 2 * NCAPS * sizeof(u4);         // 94.37 MB
    const size_t PS = (size_t)NB * NCH * NCLS * KDO * sizeof(float);      //  1.47 MB
    const size_t need = WT + XH + UT + 3 * PS;                            // ~106 MB

    if (ws_size >= need) {
        char* p = (char*)d_ws;
        u4* Wt    = (u4*)p;    p += WT;
        u4* xp    = (u4*)p;    p += XH;
        u4* ut    = (u4*)p;    p += UT;
        float* ps0 = (float*)p; p += PS;
        float* ps1 = (float*)p; p += PS;
        float* ps2 = (float*)p;

        k_pack<<<dim3(720 + 1152), dim3(256), 0, stream>>>(
            W4, Wt, (const float4*)x, xp);
        k_uhat<<<dim3(NCH, NB / BBAT, NCLS), dim3(CHUNK), 0, stream>>>(
            Wt, xp, ut, ps0);
        k_iter<<<dim3(NCH, NB), dim3(256), 0, stream>>>(ut, ps0, 0.1f, nullptr, ps1);
        k_iter<<<dim3(NCH, NB), dim3(256), 0, stream>>>(ut, ps0, 0.1f, ps1, ps2);
        k_squash<<<dim3(NB), dim3(160), 0, stream>>>(ps2, out);
    } else {
        caps_routing_fb<<<dim3(NB), dim3(256), 0, stream>>>(x, (const float*)d_in[1], out);
    }
}